// Round 9
// baseline (692.235 us; speedup 1.0000x reference)
//
#include <hip/hip_runtime.h>

// MultiBoxLoss (SSD). B=128, P=8732, C=21, N=16 (runtime-derived).
// R9: TWO dispatches. k_pre eliminated: k_hard recomputes the per-object
//     argmax in-block (~2us) and applies the force-match override as
//     CORRECTIONS to k_fused's unoverridden sums (<=16 priors/batch).
// k_fused: thread per (b,p): unoverridden match label + CE (reg-resident,
//          C=21 unrolled) + SL1 + conf_neg; per-block partial stores.
// k_hard : block per batch: per-object argmax over P (exact cross-mult,
//          first-index ties) -> last-wins dedupe -> correction deltas;
//          reg-resident exact top-k (4-ary search on float bits) with
//          overridden conf zeroed in regs; ticket finalize writes out[0].
// ws: conf[B*P] f32, locpart/pospart[nloc] f32, nppart[nloc] i32,
//     hardpart/locfix/posfix[B] f32, nposc[B] i32, acc[2] u32 (ticket).
// acc zeroed by k_fused block(0,0) (kernel-boundary visible to k_hard).

#define MAXN 16
#define MAXE 16   // max ceil(P/1024) supported by k_hard

__device__ __forceinline__ float sl1f(float d) {
    float ad = fabsf(d);
    return ad < 1.0f ? 0.5f * d * d : ad - 0.5f;
}

// Thread per (b,p), grid (nchunk, B). CT>0: compile-time class count.
template<int CT>
__global__ __launch_bounds__(256) void k_fused(
    const float* __restrict__ plocs,   // [B,P,4]
    const float* __restrict__ scores,  // [B*P, C]
    const float* __restrict__ boxes,   // [B,N,4]
    const int*   __restrict__ labels,  // [B,N]
    const float* __restrict__ priors,  // [P,4]
    int P, int Crt, int N, int nchunk,
    float* __restrict__ conf_out,      // [B,P] conf_neg (unoverridden)
    float* __restrict__ locpart,       // [B*nchunk]
    float* __restrict__ pospart,       // [B*nchunk]
    int*   __restrict__ nppart,        // [B*nchunk]
    unsigned* __restrict__ acc)        // [2] zeroed by block (0,0)
{
    const int C = CT > 0 ? CT : Crt;
    extern __shared__ float sh[];      // 256*C floats (score rows)
    __shared__ float sx1[MAXN], sy1[MAXN], sx2[MAXN], sy2[MAXN], sba[MAXN];
    __shared__ int   blab[MAXN];
    __shared__ float redf[4], redp[4];
    __shared__ int   redi[4];

    const int b = blockIdx.y;
    const int tid = threadIdx.x;
    const int lane = tid & 63, wid = tid >> 6;
    int Nc = N > MAXN ? MAXN : N;
    const int p0 = blockIdx.x * 256;
    const int rows = min(256, P - p0);

    if (blockIdx.x == 0 && b == 0 && tid < 2) acc[tid] = 0u;

    if (tid < Nc) {
        const float* bp = boxes + ((size_t)b * N + tid) * 4;
        float x1 = bp[0], y1 = bp[1], x2 = bp[2], y2 = bp[3];
        sx1[tid] = x1; sy1[tid] = y1; sx2[tid] = x2; sy2[tid] = y2;
        sba[tid] = (x2 - x1) * (y2 - y1);
        blab[tid] = labels[(size_t)b * N + tid];
    }

    // Stage this block's score rows, coalesced float4 (256*C % 4 == 0).
    {
        const size_t f4base = ((size_t)b * P + p0) * C / 4;
        const int f4cnt = (rows * C + 3) / 4;
        const float4* __restrict__ s4 = (const float4*)scores;
        for (int j = tid; j < f4cnt; j += 256)
            ((float4*)sh)[j] = s4[f4base + j];
    }
    __syncthreads();

    const int p = p0 + tid;
    float locs = 0.0f, posc = 0.0f, conf = 0.0f;
    int np = 0;
    if (p < P) {
        float4 pr = ((const float4*)priors)[p];
        float px1 = pr.x - pr.z * 0.5f, py1 = pr.y - pr.w * 0.5f;
        float px2 = pr.x + pr.z * 0.5f, py2 = pr.y + pr.w * 0.5f;
        float parea = (px2 - px1) * (py2 - py1);
        // argmax over objects, cross-mult (in/un > bi/bu <=> in*bu > bi*un)
        float bi = -1.0f, bu = 1.0f; int bestn = 0;
#pragma unroll
        for (int n = 0; n < MAXN; n++) {
            if (n < Nc) {
                float iw = fmaxf(fminf(sx2[n], px2) - fmaxf(sx1[n], px1), 0.0f);
                float ih = fmaxf(fminf(sy2[n], py2) - fmaxf(sy1[n], py1), 0.0f);
                float in = iw * ih;
                float un = sba[n] + parea - in;
                if (in * bu > bi * un) { bi = in; bu = un; bestn = n; }
            }
        }
        const int lab = (bi < 0.5f * bu) ? 0 : blab[bestn];  // NO override here

        // CE from staged row; single LDS->reg pass on the CT path
        const float* r = sh + tid * C;
        float ce;
        if constexpr (CT > 0) {
            float rv[CT];
#pragma unroll
            for (int c = 0; c < CT; c++) rv[c] = r[c];
            float m = -3.402823466e38f;
#pragma unroll
            for (int c = 0; c < CT; c++) m = fmaxf(m, rv[c]);
            float sum = 0.0f;
#pragma unroll
            for (int c = 0; c < CT; c++) sum += __expf(rv[c] - m);
            ce = m + __logf(sum) - r[lab];     // r[lab]: dynamic -> LDS read
        } else {
            float m = -3.402823466e38f;
            for (int c = 0; c < C; c++) m = fmaxf(m, r[c]);
            float sum = 0.0f;
            for (int c = 0; c < C; c++) sum += __expf(r[c] - m);
            ce = m + __logf(sum) - r[lab];
        }

        if (lab != 0) {
            posc = ce; np = 1;
            int n = bestn;
            float cx = (sx1[n] + sx2[n]) * 0.5f, cy = (sy1[n] + sy2[n]) * 0.5f;
            float w = sx2[n] - sx1[n], h = sy2[n] - sy1[n];
            float g0 = (cx - pr.x) / (pr.z / 10.0f);
            float g1 = (cy - pr.y) / (pr.w / 10.0f);
            float g2 = logf(w / pr.z) * 5.0f;
            float g3 = logf(h / pr.w) * 5.0f;
            float4 pl = ((const float4*)plocs)[(size_t)b * P + p];
            locs = sl1f(pl.x - g0) + sl1f(pl.y - g1) + sl1f(pl.z - g2) + sl1f(pl.w - g3);
        } else {
            conf = ce;
        }
        conf_out[(size_t)b * P + p] = conf;
    }
#pragma unroll
    for (int off = 32; off > 0; off >>= 1) {
        locs += __shfl_down(locs, off);
        posc += __shfl_down(posc, off);
        np   += __shfl_down(np, off);
    }
    if (lane == 0) { redf[wid] = locs; redp[wid] = posc; redi[wid] = np; }
    __syncthreads();
    if (tid == 0) {
        locpart[b * nchunk + blockIdx.x] = redf[0] + redf[1] + redf[2] + redf[3];
        pospart[b * nchunk + blockIdx.x] = redp[0] + redp[1] + redp[2] + redp[3];
        nppart [b * nchunk + blockIdx.x] = redi[0] + redi[1] + redi[2] + redi[3];
    }
}

// Block per batch (1024 thr). Phases: A) per-object argmax over P priors
// (exact cross-mult, first-index ties); B) last-wins dedupe + correction
// deltas vs k_fused's unoverridden sums; C) npos; D) exact top-k with
// overridden conf zeroed in regs; E) per-block outputs + ticket finalize.
__global__ __launch_bounds__(1024, 4) void k_hard(
    const float* __restrict__ plocs,
    const float* __restrict__ scores,
    const float* __restrict__ boxes,
    const int*   __restrict__ labels,
    const float* __restrict__ priors,
    const float* __restrict__ conf,     // [B,P] unoverridden conf_neg
    const float* __restrict__ locpart,  // [nloc]
    const float* __restrict__ pospart,  // [nloc]
    const int*   __restrict__ nppart,   // [nloc]
    int P, int C, int N, int nchunk, int B, int nloc,
    float* __restrict__ hardpart,       // [B]
    float* __restrict__ locfix,         // [B]
    float* __restrict__ posfix,         // [B]
    int*   __restrict__ nposc,          // [B]
    unsigned* __restrict__ acc,         // [2]: [1]=ticket
    float* __restrict__ out)
{
    __shared__ float sx1[MAXN], sy1[MAXN], sx2[MAXN], sy2[MAXN], sba[MAXN];
    __shared__ int   blab[MAXN];
    __shared__ float win[16 * MAXN], wun[16 * MAXN];
    __shared__ int   widx[16 * MAXN];
    __shared__ int   fixp[MAXN];
    __shared__ float rfa[16], rfb[16];
    __shared__ int   ria[16], rib[16];
    __shared__ int   srch[16 * 3];
    __shared__ int   s_np, is_last;
    __shared__ float s_dloc, s_dpos;

    const int b = blockIdx.x, tid = threadIdx.x;
    const int lane = tid & 63, wid = tid >> 6;
    const int nthr = blockDim.x, nw = nthr >> 6;
    int Nc = N > MAXN ? MAXN : N;

    if (tid < Nc) {
        const float* bp = boxes + ((size_t)b * N + tid) * 4;
        float x1 = bp[0], y1 = bp[1], x2 = bp[2], y2 = bp[3];
        sx1[tid] = x1; sy1[tid] = y1; sx2[tid] = x2; sy2[tid] = y2;
        sba[tid] = (x2 - x1) * (y2 - y1);
        blab[tid] = labels[(size_t)b * N + tid];
    }
    __syncthreads();

    // Phase A: per-object argmax over P priors (cross-mult exact).
    // Per-thread ascending p + strict > keeps first index; cross-thread
    // reduce prefers better ratio then smaller index -> global first-index.
    {
        float bin[MAXN], bun[MAXN]; int bix[MAXN];
#pragma unroll
        for (int n = 0; n < MAXN; n++) { bin[n] = -1.0f; bun[n] = 1.0f; bix[n] = 0x7fffffff; }
        for (int p = tid; p < P; p += nthr) {
            float4 pr = ((const float4*)priors)[p];
            float px1 = pr.x - pr.z * 0.5f, py1 = pr.y - pr.w * 0.5f;
            float px2 = pr.x + pr.z * 0.5f, py2 = pr.y + pr.w * 0.5f;
            float parea = (px2 - px1) * (py2 - py1);
#pragma unroll
            for (int n = 0; n < MAXN; n++) {
                if (n < Nc) {
                    float iw = fmaxf(fminf(sx2[n], px2) - fmaxf(sx1[n], px1), 0.0f);
                    float ih = fmaxf(fminf(sy2[n], py2) - fmaxf(sy1[n], py1), 0.0f);
                    float in = iw * ih;
                    float un = sba[n] + parea - in;
                    if (in * bun[n] > bin[n] * un) { bin[n] = in; bun[n] = un; bix[n] = p; }
                }
            }
        }
#pragma unroll
        for (int n = 0; n < MAXN; n++) {
            if (n < Nc) {
                float i_ = bin[n], u_ = bun[n]; int x_ = bix[n];
#pragma unroll
                for (int off = 32; off > 0; off >>= 1) {
                    float oi = __shfl_down(i_, off);
                    float ou = __shfl_down(u_, off);
                    int   ox = __shfl_down(x_, off);
                    float a = oi * u_, c = i_ * ou;
                    if (a > c || (a == c && ox < x_)) { i_ = oi; u_ = ou; x_ = ox; }
                }
                if (lane == 0) { win[wid * MAXN + n] = i_; wun[wid * MAXN + n] = u_; widx[wid * MAXN + n] = x_; }
            }
        }
        __syncthreads();
        if (tid < Nc) {
            float i_ = win[tid], u_ = wun[tid]; int x_ = widx[tid];
            for (int w = 1; w < nw; w++) {
                float oi = win[w * MAXN + tid], ou = wun[w * MAXN + tid];
                int   ox = widx[w * MAXN + tid];
                float a = oi * u_, c = i_ * ou;
                if (a > c || (a == c && ox < x_)) { i_ = oi; u_ = ou; x_ = ox; }
            }
            fixp[tid] = x_;
        }
        __syncthreads();
    }

    // Phase B: corrections for overridden priors (last-wins dedupe).
    // Recompute k_fused's unoverridden state with IDENTICAL code/order.
    float dloc = 0.0f, dpos = 0.0f; int dnp = 0;
    if (tid < Nc) {
        int pn = fixp[tid];
        bool active = true;
        for (int n2 = tid + 1; n2 < Nc; n2++) if (fixp[n2] == pn) active = false;
        if (active) {
            float4 pr = ((const float4*)priors)[pn];
            float px1 = pr.x - pr.z * 0.5f, py1 = pr.y - pr.w * 0.5f;
            float px2 = pr.x + pr.z * 0.5f, py2 = pr.y + pr.w * 0.5f;
            float parea = (px2 - px1) * (py2 - py1);
            float bi = -1.0f, bu = 1.0f; int bestn = 0;
#pragma unroll
            for (int n = 0; n < MAXN; n++) {
                if (n < Nc) {
                    float iw = fmaxf(fminf(sx2[n], px2) - fmaxf(sx1[n], px1), 0.0f);
                    float ih = fmaxf(fminf(sy2[n], py2) - fmaxf(sy1[n], py1), 0.0f);
                    float in = iw * ih;
                    float un = sba[n] + parea - in;
                    if (in * bu > bi * un) { bi = in; bu = un; bestn = n; }
                }
            }
            const int lab0 = (bi < 0.5f * bu) ? 0 : blab[bestn];

            const float* r = scores + ((size_t)b * P + pn) * C;
            float m = -3.402823466e38f;
            for (int c = 0; c < C; c++) m = fmaxf(m, r[c]);
            float sum = 0.0f;
            for (int c = 0; c < C; c++) sum += __expf(r[c] - m);
            const float lse = m + __logf(sum);

            float4 pl = ((const float4*)plocs)[(size_t)b * P + pn];
            // new contribution: label = blab[tid] (always != 0), box tid
            {
                int n = tid;
                float cx = (sx1[n] + sx2[n]) * 0.5f, cy = (sy1[n] + sy2[n]) * 0.5f;
                float w = sx2[n] - sx1[n], h = sy2[n] - sy1[n];
                float g0 = (cx - pr.x) / (pr.z / 10.0f);
                float g1 = (cy - pr.y) / (pr.w / 10.0f);
                float g2 = logf(w / pr.z) * 5.0f;
                float g3 = logf(h / pr.w) * 5.0f;
                dloc = sl1f(pl.x - g0) + sl1f(pl.y - g1) + sl1f(pl.z - g2) + sl1f(pl.w - g3);
                dpos = lse - r[blab[n]];
            }
            if (lab0 != 0) {       // remove old positive contribution
                int n = bestn;
                float cx = (sx1[n] + sx2[n]) * 0.5f, cy = (sy1[n] + sy2[n]) * 0.5f;
                float w = sx2[n] - sx1[n], h = sy2[n] - sy1[n];
                float g0 = (cx - pr.x) / (pr.z / 10.0f);
                float g1 = (cy - pr.y) / (pr.w / 10.0f);
                float g2 = logf(w / pr.z) * 5.0f;
                float g3 = logf(h / pr.w) * 5.0f;
                dloc -= sl1f(pl.x - g0) + sl1f(pl.y - g1) + sl1f(pl.z - g2) + sl1f(pl.w - g3);
                dpos -= lse - r[lab0];
            } else {
                dnp = 1;           // prior flips negative -> positive
            }
        }
    }
    // Phase C: npos partials (nchunk <= nthr assumed; contributors any wave)
    int npp = 0;
    for (int i = tid; i < nchunk; i += nthr) npp += nppart[b * nchunk + i];
#pragma unroll
    for (int off = 32; off > 0; off >>= 1) {
        dloc += __shfl_down(dloc, off);
        dpos += __shfl_down(dpos, off);
        dnp  += __shfl_down(dnp, off);
        npp  += __shfl_down(npp, off);
    }
    if (lane == 0) { rfa[wid] = dloc; rfb[wid] = dpos; ria[wid] = dnp; rib[wid] = npp; }
    __syncthreads();
    if (tid == 0) {
        float L = 0.0f, Pp = 0.0f; int a = 0, c = 0;
        for (int w = 0; w < nw; w++) { L += rfa[w]; Pp += rfb[w]; a += ria[w]; c += rib[w]; }
        s_dloc = L; s_dpos = Pp; s_np = c + a;
    }
    __syncthreads();
    const int npos_b = s_np;
    long long kk = (long long)npos_b * 3;
    int k = kk > P ? P : (int)kk;       // block-uniform

    // Phase D: exact top-k sum over conf with overridden priors zeroed.
    float S = 0.0f;
    const int ne = (P + nthr - 1) / nthr;
    if (k > 0) {
        unsigned e[MAXE];
#pragma unroll
        for (int j = 0; j < MAXE; j++) {
            int p = j * nthr + tid;
            e[j] = (j < ne && p < P) ? __float_as_uint(conf[(size_t)b * P + p]) : 0u;
        }
#pragma unroll
        for (int j = 0; j < MAXE; j++) {
            if (j < ne) {
                int p = j * nthr + tid;
                for (int n = 0; n < Nc; n++) if (fixp[n] == p) e[j] = 0u;
            }
        }
        // largest bit pattern t with count(x >= t) >= k == exact k-th largest
        unsigned lo = 0u, hi = 0x7F800000u;
        while (lo < hi) {
            unsigned span = hi - lo;
            if (span >= 8) {
                unsigned q = span >> 2;
                unsigned m1 = lo + q, m2 = lo + 2 * q, m3 = lo + 3 * q;
                int c1 = 0, c2 = 0, c3 = 0;
#pragma unroll
                for (int j = 0; j < MAXE; j++) {
                    if (j < ne) {
                        unsigned v = e[j];
                        c1 += (int)__popcll(__ballot(v >= m1));
                        c2 += (int)__popcll(__ballot(v >= m2));
                        c3 += (int)__popcll(__ballot(v >= m3));
                    }
                }
                if (lane == 0) { srch[wid * 3] = c1; srch[wid * 3 + 1] = c2; srch[wid * 3 + 2] = c3; }
                __syncthreads();
                int C1 = 0, C2 = 0, C3 = 0;
                for (int w = 0; w < nw; w++) {
                    C1 += srch[w * 3]; C2 += srch[w * 3 + 1]; C3 += srch[w * 3 + 2];
                }
                __syncthreads();
                if      (C3 >= k) lo = m3;
                else if (C2 >= k) { lo = m2; hi = m3 - 1; }
                else if (C1 >= k) { lo = m1; hi = m2 - 1; }
                else              hi = m1 - 1;
            } else {
                unsigned mid = lo + ((span + 1) >> 1);
                int c = 0;
#pragma unroll
                for (int j = 0; j < MAXE; j++)
                    if (j < ne) c += (int)__popcll(__ballot(e[j] >= mid));
                if (lane == 0) srch[wid * 3] = c;
                __syncthreads();
                int Cc = 0;
                for (int w = 0; w < nw; w++) Cc += srch[w * 3];
                __syncthreads();
                if (Cc >= k) lo = mid; else hi = mid - 1;
            }
        }
        float t = __uint_as_float(lo);
        float sgt = 0.0f; int cgt = 0;
#pragma unroll
        for (int j = 0; j < MAXE; j++) {
            if (j < ne) {
                float v = __uint_as_float(e[j]);
                if (v > t) { sgt += v; cgt++; }
            }
        }
#pragma unroll
        for (int off = 32; off > 0; off >>= 1) {
            sgt += __shfl_down(sgt, off);
            cgt += __shfl_down(cgt, off);
        }
        if (lane == 0) { rfa[wid] = sgt; ria[wid] = cgt; }
        __syncthreads();
        if (tid == 0) {
            int Cg = 0;
            for (int w = 0; w < nw; w++) { S += rfa[w]; Cg += ria[w]; }
            S += (float)(k - Cg) * t;   // ties at t handled exactly
        }
        __syncthreads();
    }

    // Phase E: per-block outputs + ticket finalize
    if (tid == 0) {
        hardpart[b] = S;
        locfix[b] = s_dloc;
        posfix[b] = s_dpos;
        nposc[b] = npos_b;
        __threadfence();
        unsigned tk = atomicAdd(acc + 1, 1u);
        is_last = (tk == (unsigned)gridDim.x - 1) ? 1 : 0;
    }
    __syncthreads();
    if (is_last) {
        __threadfence();   // acquire: see all blocks' stores
        float lp = 0.0f, pp = 0.0f, hp = 0.0f; int np = 0;
        for (int i = tid; i < nloc; i += nthr) { lp += locpart[i]; pp += pospart[i]; }
        for (int i = tid; i < B; i += nthr) {
            lp += locfix[i]; pp += posfix[i]; hp += hardpart[i]; np += nposc[i];
        }
#pragma unroll
        for (int off = 32; off > 0; off >>= 1) {
            lp += __shfl_down(lp, off);
            pp += __shfl_down(pp, off);
            hp += __shfl_down(hp, off);
            np += __shfl_down(np, off);
        }
        if (lane == 0) { rfa[wid] = lp; rfb[wid] = pp; win[wid] = hp; ria[wid] = np; }
        __syncthreads();
        if (tid == 0) {
            float L = 0.0f, Pp = 0.0f, H = 0.0f; int Np = 0;
            for (int w = 0; w < nw; w++) { L += rfa[w]; Pp += rfb[w]; H += win[w]; Np += ria[w]; }
            float npf = (float)Np;
            out[0] = (H + Pp) / npf + L / (npf * 4.0f);
        }
    }
}

extern "C" void kernel_launch(void* const* d_in, const int* in_sizes, int n_in,
                              void* d_out, int out_size, void* d_ws, size_t ws_size,
                              hipStream_t stream)
{
    const float* plocs  = (const float*)d_in[0];
    const float* scores = (const float*)d_in[1];
    const float* boxes  = (const float*)d_in[2];
    const int*   labels = (const int*)d_in[3];
    const float* priors = (const float*)d_in[4];

    int P = in_sizes[4] / 4;
    int B = in_sizes[0] / (P * 4);
    int C = in_sizes[1] / (in_sizes[0] / 4);
    int N = in_sizes[3] / B;
    int nchunk = (P + 255) / 256;
    int nloc = B * nchunk;

    char* w = (char*)d_ws;
    float* conf     = (float*)w;  w += (size_t)B * P * sizeof(float);
    float* locpart  = (float*)w;  w += (size_t)nloc * sizeof(float);
    float* pospart  = (float*)w;  w += (size_t)nloc * sizeof(float);
    int*   nppart   = (int*)w;    w += (size_t)nloc * sizeof(int);
    float* hardpart = (float*)w;  w += (size_t)B * sizeof(float);
    float* locfix   = (float*)w;  w += (size_t)B * sizeof(float);
    float* posfix   = (float*)w;  w += (size_t)B * sizeof(float);
    int*   nposc    = (int*)w;    w += (size_t)B * sizeof(int);
    w = (char*)(((uintptr_t)w + 63) & ~(uintptr_t)63);
    unsigned* acc   = (unsigned*)w;   // 2 words

    dim3 ga(nchunk, B);
    size_t smf = (size_t)256 * C * sizeof(float);
    if (C == 21) {
        k_fused<21><<<ga, 256, smf, stream>>>(plocs, scores, boxes, labels, priors,
                                              P, C, N, nchunk, conf,
                                              locpart, pospart, nppart, acc);
    } else {
        k_fused<0><<<ga, 256, smf, stream>>>(plocs, scores, boxes, labels, priors,
                                             P, C, N, nchunk, conf,
                                             locpart, pospart, nppart, acc);
    }

    k_hard<<<B, 1024, 0, stream>>>(plocs, scores, boxes, labels, priors,
                                   conf, locpart, pospart, nppart,
                                   P, C, N, nchunk, B, nloc,
                                   hardpart, locfix, posfix, nposc,
                                   acc, (float*)d_out);
}

// Round 10
// 233.611 us; speedup vs baseline: 2.9632x; 2.9632x over previous
//
#include <hip/hip_runtime.h>

// MultiBoxLoss (SSD). B=128, P=8732, C=21, N=16 (runtime-derived).
// R10: R9's 2-dispatch design with the k_hard phase-A spill fixed:
//   1024-thread blocks cap at 64 VGPRs (compiler), so R9's per-thread
//   bin/bun/bix[16] arrays (48 regs) spilled 858MB to scratch (615us).
//   Phase A is now ONE WAVE PER OBJECT: 3 scalars/thread, no arrays.
// k_fused: thread per (b,p): unoverridden match label + CE (reg-resident,
//          C=21 unrolled) + SL1 + conf_neg; per-block partial stores.
// k_hard : block per batch: A) wave-per-object argmax over P (cross-mult,
//          first-index ties) B) last-wins dedupe + correction deltas
//          C) npos D) reg-resident exact top-k (overridden conf zeroed)
//          E) ticket finalize writes out[0].
// ws: conf[B*P] f32, locpart/pospart[nloc] f32, nppart[nloc] i32,
//     hardpart/locfix/posfix[B] f32, nposc[B] i32, acc[2] u32 (ticket).

#define MAXN 16
#define MAXE 16   // max ceil(P/1024) supported by k_hard

__device__ __forceinline__ float sl1f(float d) {
    float ad = fabsf(d);
    return ad < 1.0f ? 0.5f * d * d : ad - 0.5f;
}

// Thread per (b,p), grid (nchunk, B). CT>0: compile-time class count.
template<int CT>
__global__ __launch_bounds__(256) void k_fused(
    const float* __restrict__ plocs,   // [B,P,4]
    const float* __restrict__ scores,  // [B*P, C]
    const float* __restrict__ boxes,   // [B,N,4]
    const int*   __restrict__ labels,  // [B,N]
    const float* __restrict__ priors,  // [P,4]
    int P, int Crt, int N, int nchunk,
    float* __restrict__ conf_out,      // [B,P] conf_neg (unoverridden)
    float* __restrict__ locpart,       // [B*nchunk]
    float* __restrict__ pospart,       // [B*nchunk]
    int*   __restrict__ nppart,        // [B*nchunk]
    unsigned* __restrict__ acc)        // [2] zeroed by block (0,0)
{
    const int C = CT > 0 ? CT : Crt;
    extern __shared__ float sh[];      // 256*C floats (score rows)
    __shared__ float sx1[MAXN], sy1[MAXN], sx2[MAXN], sy2[MAXN], sba[MAXN];
    __shared__ int   blab[MAXN];
    __shared__ float redf[4], redp[4];
    __shared__ int   redi[4];

    const int b = blockIdx.y;
    const int tid = threadIdx.x;
    const int lane = tid & 63, wid = tid >> 6;
    int Nc = N > MAXN ? MAXN : N;
    const int p0 = blockIdx.x * 256;
    const int rows = min(256, P - p0);

    if (blockIdx.x == 0 && b == 0 && tid < 2) acc[tid] = 0u;

    if (tid < Nc) {
        const float* bp = boxes + ((size_t)b * N + tid) * 4;
        float x1 = bp[0], y1 = bp[1], x2 = bp[2], y2 = bp[3];
        sx1[tid] = x1; sy1[tid] = y1; sx2[tid] = x2; sy2[tid] = y2;
        sba[tid] = (x2 - x1) * (y2 - y1);
        blab[tid] = labels[(size_t)b * N + tid];
    }

    // Stage this block's score rows, coalesced float4 (256*C % 4 == 0).
    {
        const size_t f4base = ((size_t)b * P + p0) * C / 4;
        const int f4cnt = (rows * C + 3) / 4;
        const float4* __restrict__ s4 = (const float4*)scores;
        for (int j = tid; j < f4cnt; j += 256)
            ((float4*)sh)[j] = s4[f4base + j];
    }
    __syncthreads();

    const int p = p0 + tid;
    float locs = 0.0f, posc = 0.0f, conf = 0.0f;
    int np = 0;
    if (p < P) {
        float4 pr = ((const float4*)priors)[p];
        float px1 = pr.x - pr.z * 0.5f, py1 = pr.y - pr.w * 0.5f;
        float px2 = pr.x + pr.z * 0.5f, py2 = pr.y + pr.w * 0.5f;
        float parea = (px2 - px1) * (py2 - py1);
        // argmax over objects, cross-mult (in/un > bi/bu <=> in*bu > bi*un)
        float bi = -1.0f, bu = 1.0f; int bestn = 0;
#pragma unroll
        for (int n = 0; n < MAXN; n++) {
            if (n < Nc) {
                float iw = fmaxf(fminf(sx2[n], px2) - fmaxf(sx1[n], px1), 0.0f);
                float ih = fmaxf(fminf(sy2[n], py2) - fmaxf(sy1[n], py1), 0.0f);
                float in = iw * ih;
                float un = sba[n] + parea - in;
                if (in * bu > bi * un) { bi = in; bu = un; bestn = n; }
            }
        }
        const int lab = (bi < 0.5f * bu) ? 0 : blab[bestn];  // NO override here

        // CE from staged row; single LDS->reg pass on the CT path
        const float* r = sh + tid * C;
        float ce;
        if constexpr (CT > 0) {
            float rv[CT];
#pragma unroll
            for (int c = 0; c < CT; c++) rv[c] = r[c];
            float m = -3.402823466e38f;
#pragma unroll
            for (int c = 0; c < CT; c++) m = fmaxf(m, rv[c]);
            float sum = 0.0f;
#pragma unroll
            for (int c = 0; c < CT; c++) sum += __expf(rv[c] - m);
            ce = m + __logf(sum) - r[lab];     // r[lab]: dynamic -> LDS read
        } else {
            float m = -3.402823466e38f;
            for (int c = 0; c < C; c++) m = fmaxf(m, r[c]);
            float sum = 0.0f;
            for (int c = 0; c < C; c++) sum += __expf(r[c] - m);
            ce = m + __logf(sum) - r[lab];
        }

        if (lab != 0) {
            posc = ce; np = 1;
            int n = bestn;
            float cx = (sx1[n] + sx2[n]) * 0.5f, cy = (sy1[n] + sy2[n]) * 0.5f;
            float w = sx2[n] - sx1[n], h = sy2[n] - sy1[n];
            float g0 = (cx - pr.x) / (pr.z / 10.0f);
            float g1 = (cy - pr.y) / (pr.w / 10.0f);
            float g2 = logf(w / pr.z) * 5.0f;
            float g3 = logf(h / pr.w) * 5.0f;
            float4 pl = ((const float4*)plocs)[(size_t)b * P + p];
            locs = sl1f(pl.x - g0) + sl1f(pl.y - g1) + sl1f(pl.z - g2) + sl1f(pl.w - g3);
        } else {
            conf = ce;
        }
        conf_out[(size_t)b * P + p] = conf;
    }
#pragma unroll
    for (int off = 32; off > 0; off >>= 1) {
        locs += __shfl_down(locs, off);
        posc += __shfl_down(posc, off);
        np   += __shfl_down(np, off);
    }
    if (lane == 0) { redf[wid] = locs; redp[wid] = posc; redi[wid] = np; }
    __syncthreads();
    if (tid == 0) {
        locpart[b * nchunk + blockIdx.x] = redf[0] + redf[1] + redf[2] + redf[3];
        pospart[b * nchunk + blockIdx.x] = redp[0] + redp[1] + redp[2] + redp[3];
        nppart [b * nchunk + blockIdx.x] = redi[0] + redi[1] + redi[2] + redi[3];
    }
}

// Block per batch (1024 thr = 16 waves). NO per-thread arrays except e[MAXE]
// (16 VGPRs) -- 1024-thread blocks cap at 64 VGPRs, arrays spill (R2, R9).
__global__ __launch_bounds__(1024, 4) void k_hard(
    const float* __restrict__ plocs,
    const float* __restrict__ scores,
    const float* __restrict__ boxes,
    const int*   __restrict__ labels,
    const float* __restrict__ priors,
    const float* __restrict__ conf,     // [B,P] unoverridden conf_neg
    const float* __restrict__ locpart,  // [nloc]
    const float* __restrict__ pospart,  // [nloc]
    const int*   __restrict__ nppart,   // [nloc]
    int P, int C, int N, int nchunk, int B, int nloc,
    float* __restrict__ hardpart,       // [B]
    float* __restrict__ locfix,         // [B]
    float* __restrict__ posfix,         // [B]
    int*   __restrict__ nposc,          // [B]
    unsigned* __restrict__ acc,         // [2]: [1]=ticket
    float* __restrict__ out)
{
    __shared__ float sx1[MAXN], sy1[MAXN], sx2[MAXN], sy2[MAXN], sba[MAXN];
    __shared__ int   blab[MAXN];
    __shared__ int   fixp[MAXN];
    __shared__ float rfa[16], rfb[16];
    __shared__ int   ria[16], rib[16];
    __shared__ float rfc[16];
    __shared__ int   srch[16 * 3];
    __shared__ int   s_np, is_last;
    __shared__ float s_dloc, s_dpos;

    const int b = blockIdx.x, tid = threadIdx.x;
    const int lane = tid & 63, wid = tid >> 6;
    const int nthr = blockDim.x, nw = nthr >> 6;
    int Nc = N > MAXN ? MAXN : N;

    if (tid < Nc) {
        const float* bp = boxes + ((size_t)b * N + tid) * 4;
        float x1 = bp[0], y1 = bp[1], x2 = bp[2], y2 = bp[3];
        sx1[tid] = x1; sy1[tid] = y1; sx2[tid] = x2; sy2[tid] = y2;
        sba[tid] = (x2 - x1) * (y2 - y1);
        blab[tid] = labels[(size_t)b * N + tid];
    }
    __syncthreads();

    // Phase A: per-object argmax over P priors -- ONE WAVE PER OBJECT.
    // 3 scalars per thread, no arrays. Per-lane ascending p (stride 64) with
    // strict > keeps first index; wave reduce prefers better ratio then
    // smaller index -> exact global first-index argmax (cross-mult compare).
    for (int n = wid; n < Nc; n += nw) {
        const float bx1 = sx1[n], by1 = sy1[n], bx2 = sx2[n], by2 = sy2[n];
        const float ba = sba[n];
        float bi = -1.0f, bu = 1.0f; int bx = 0x7fffffff;
#pragma unroll 4
        for (int p = lane; p < P; p += 64) {
            float4 pr = ((const float4*)priors)[p];
            float px1 = pr.x - pr.z * 0.5f, py1 = pr.y - pr.w * 0.5f;
            float px2 = pr.x + pr.z * 0.5f, py2 = pr.y + pr.w * 0.5f;
            float parea = (px2 - px1) * (py2 - py1);
            float iw = fmaxf(fminf(bx2, px2) - fmaxf(bx1, px1), 0.0f);
            float ih = fmaxf(fminf(by2, py2) - fmaxf(by1, py1), 0.0f);
            float in = iw * ih;
            float un = ba + parea - in;
            if (in * bu > bi * un) { bi = in; bu = un; bx = p; }
        }
#pragma unroll
        for (int off = 32; off > 0; off >>= 1) {
            float oi = __shfl_down(bi, off);
            float ou = __shfl_down(bu, off);
            int   ox = __shfl_down(bx, off);
            float a = oi * bu, c = bi * ou;
            if (a > c || (a == c && ox < bx)) { bi = oi; bu = ou; bx = ox; }
        }
        if (lane == 0) fixp[n] = bx;
    }
    __syncthreads();

    // Phase B: corrections for overridden priors (last-wins dedupe).
    // Recompute k_fused's unoverridden state with IDENTICAL code/order.
    float dloc = 0.0f, dpos = 0.0f; int dnp = 0;
    if (tid < Nc) {
        int pn = fixp[tid];
        bool active = true;
        for (int n2 = tid + 1; n2 < Nc; n2++) if (fixp[n2] == pn) active = false;
        if (active) {
            float4 pr = ((const float4*)priors)[pn];
            float px1 = pr.x - pr.z * 0.5f, py1 = pr.y - pr.w * 0.5f;
            float px2 = pr.x + pr.z * 0.5f, py2 = pr.y + pr.w * 0.5f;
            float parea = (px2 - px1) * (py2 - py1);
            float bi = -1.0f, bu = 1.0f; int bestn = 0;
#pragma unroll
            for (int n = 0; n < MAXN; n++) {
                if (n < Nc) {
                    float iw = fmaxf(fminf(sx2[n], px2) - fmaxf(sx1[n], px1), 0.0f);
                    float ih = fmaxf(fminf(sy2[n], py2) - fmaxf(sy1[n], py1), 0.0f);
                    float in = iw * ih;
                    float un = sba[n] + parea - in;
                    if (in * bu > bi * un) { bi = in; bu = un; bestn = n; }
                }
            }
            const int lab0 = (bi < 0.5f * bu) ? 0 : blab[bestn];

            const float* r = scores + ((size_t)b * P + pn) * C;
            float m = -3.402823466e38f;
            for (int c = 0; c < C; c++) m = fmaxf(m, r[c]);
            float sum = 0.0f;
            for (int c = 0; c < C; c++) sum += __expf(r[c] - m);
            const float lse = m + __logf(sum);

            float4 pl = ((const float4*)plocs)[(size_t)b * P + pn];
            // new contribution: label = blab[tid] (always != 0), box tid
            {
                int n = tid;
                float cx = (sx1[n] + sx2[n]) * 0.5f, cy = (sy1[n] + sy2[n]) * 0.5f;
                float w = sx2[n] - sx1[n], h = sy2[n] - sy1[n];
                float g0 = (cx - pr.x) / (pr.z / 10.0f);
                float g1 = (cy - pr.y) / (pr.w / 10.0f);
                float g2 = logf(w / pr.z) * 5.0f;
                float g3 = logf(h / pr.w) * 5.0f;
                dloc = sl1f(pl.x - g0) + sl1f(pl.y - g1) + sl1f(pl.z - g2) + sl1f(pl.w - g3);
                dpos = lse - r[blab[n]];
            }
            if (lab0 != 0) {       // remove old positive contribution
                int n = bestn;
                float cx = (sx1[n] + sx2[n]) * 0.5f, cy = (sy1[n] + sy2[n]) * 0.5f;
                float w = sx2[n] - sx1[n], h = sy2[n] - sy1[n];
                float g0 = (cx - pr.x) / (pr.z / 10.0f);
                float g1 = (cy - pr.y) / (pr.w / 10.0f);
                float g2 = logf(w / pr.z) * 5.0f;
                float g3 = logf(h / pr.w) * 5.0f;
                dloc -= sl1f(pl.x - g0) + sl1f(pl.y - g1) + sl1f(pl.z - g2) + sl1f(pl.w - g3);
                dpos -= lse - r[lab0];
            } else {
                dnp = 1;           // prior flips negative -> positive
            }
        }
    }
    // Phase C: npos partials
    int npp = 0;
    for (int i = tid; i < nchunk; i += nthr) npp += nppart[b * nchunk + i];
#pragma unroll
    for (int off = 32; off > 0; off >>= 1) {
        dloc += __shfl_down(dloc, off);
        dpos += __shfl_down(dpos, off);
        dnp  += __shfl_down(dnp, off);
        npp  += __shfl_down(npp, off);
    }
    if (lane == 0) { rfa[wid] = dloc; rfb[wid] = dpos; ria[wid] = dnp; rib[wid] = npp; }
    __syncthreads();
    if (tid == 0) {
        float L = 0.0f, Pp = 0.0f; int a = 0, c = 0;
        for (int w = 0; w < nw; w++) { L += rfa[w]; Pp += rfb[w]; a += ria[w]; c += rib[w]; }
        s_dloc = L; s_dpos = Pp; s_np = c + a;
    }
    __syncthreads();
    const int npos_b = s_np;
    long long kk = (long long)npos_b * 3;
    int k = kk > P ? P : (int)kk;       // block-uniform

    // Phase D: exact top-k sum over conf with overridden priors zeroed.
    float S = 0.0f;
    const int ne = (P + nthr - 1) / nthr;
    if (k > 0) {
        unsigned e[MAXE];
#pragma unroll
        for (int j = 0; j < MAXE; j++) {
            int p = j * nthr + tid;
            e[j] = (j < ne && p < P) ? __float_as_uint(conf[(size_t)b * P + p]) : 0u;
        }
#pragma unroll
        for (int j = 0; j < MAXE; j++) {
            if (j < ne) {
                int p = j * nthr + tid;
                for (int n = 0; n < Nc; n++) if (fixp[n] == p) e[j] = 0u;
            }
        }
        // largest bit pattern t with count(x >= t) >= k == exact k-th largest
        unsigned lo = 0u, hi = 0x7F800000u;
        while (lo < hi) {
            unsigned span = hi - lo;
            if (span >= 8) {
                unsigned q = span >> 2;
                unsigned m1 = lo + q, m2 = lo + 2 * q, m3 = lo + 3 * q;
                int c1 = 0, c2 = 0, c3 = 0;
#pragma unroll
                for (int j = 0; j < MAXE; j++) {
                    if (j < ne) {
                        unsigned v = e[j];
                        c1 += (int)__popcll(__ballot(v >= m1));
                        c2 += (int)__popcll(__ballot(v >= m2));
                        c3 += (int)__popcll(__ballot(v >= m3));
                    }
                }
                if (lane == 0) { srch[wid * 3] = c1; srch[wid * 3 + 1] = c2; srch[wid * 3 + 2] = c3; }
                __syncthreads();
                int C1 = 0, C2 = 0, C3 = 0;
                for (int w = 0; w < nw; w++) {
                    C1 += srch[w * 3]; C2 += srch[w * 3 + 1]; C3 += srch[w * 3 + 2];
                }
                __syncthreads();
                if      (C3 >= k) lo = m3;
                else if (C2 >= k) { lo = m2; hi = m3 - 1; }
                else if (C1 >= k) { lo = m1; hi = m2 - 1; }
                else              hi = m1 - 1;
            } else {
                unsigned mid = lo + ((span + 1) >> 1);
                int c = 0;
#pragma unroll
                for (int j = 0; j < MAXE; j++)
                    if (j < ne) c += (int)__popcll(__ballot(e[j] >= mid));
                if (lane == 0) srch[wid * 3] = c;
                __syncthreads();
                int Cc = 0;
                for (int w = 0; w < nw; w++) Cc += srch[w * 3];
                __syncthreads();
                if (Cc >= k) lo = mid; else hi = mid - 1;
            }
        }
        float t = __uint_as_float(lo);
        float sgt = 0.0f; int cgt = 0;
#pragma unroll
        for (int j = 0; j < MAXE; j++) {
            if (j < ne) {
                float v = __uint_as_float(e[j]);
                if (v > t) { sgt += v; cgt++; }
            }
        }
#pragma unroll
        for (int off = 32; off > 0; off >>= 1) {
            sgt += __shfl_down(sgt, off);
            cgt += __shfl_down(cgt, off);
        }
        if (lane == 0) { rfa[wid] = sgt; ria[wid] = cgt; }
        __syncthreads();
        if (tid == 0) {
            int Cg = 0;
            for (int w = 0; w < nw; w++) { S += rfa[w]; Cg += ria[w]; }
            S += (float)(k - Cg) * t;   // ties at t handled exactly
        }
        __syncthreads();
    }

    // Phase E: per-block outputs + ticket finalize
    if (tid == 0) {
        hardpart[b] = S;
        locfix[b] = s_dloc;
        posfix[b] = s_dpos;
        nposc[b] = npos_b;
        __threadfence();
        unsigned tk = atomicAdd(acc + 1, 1u);
        is_last = (tk == (unsigned)gridDim.x - 1) ? 1 : 0;
    }
    __syncthreads();
    if (is_last) {
        __threadfence();   // see all blocks' stores
        float lp = 0.0f, pp = 0.0f, hp = 0.0f; int np = 0;
        for (int i = tid; i < nloc; i += nthr) { lp += locpart[i]; pp += pospart[i]; }
        for (int i = tid; i < B; i += nthr) {
            lp += locfix[i]; pp += posfix[i]; hp += hardpart[i]; np += nposc[i];
        }
#pragma unroll
        for (int off = 32; off > 0; off >>= 1) {
            lp += __shfl_down(lp, off);
            pp += __shfl_down(pp, off);
            hp += __shfl_down(hp, off);
            np += __shfl_down(np, off);
        }
        if (lane == 0) { rfa[wid] = lp; rfb[wid] = pp; rfc[wid] = hp; ria[wid] = np; }
        __syncthreads();
        if (tid == 0) {
            float L = 0.0f, Pp = 0.0f, H = 0.0f; int Np = 0;
            for (int w = 0; w < nw; w++) { L += rfa[w]; Pp += rfb[w]; H += rfc[w]; Np += ria[w]; }
            float npf = (float)Np;
            out[0] = (H + Pp) / npf + L / (npf * 4.0f);
        }
    }
}

extern "C" void kernel_launch(void* const* d_in, const int* in_sizes, int n_in,
                              void* d_out, int out_size, void* d_ws, size_t ws_size,
                              hipStream_t stream)
{
    const float* plocs  = (const float*)d_in[0];
    const float* scores = (const float*)d_in[1];
    const float* boxes  = (const float*)d_in[2];
    const int*   labels = (const int*)d_in[3];
    const float* priors = (const float*)d_in[4];

    int P = in_sizes[4] / 4;
    int B = in_sizes[0] / (P * 4);
    int C = in_sizes[1] / (in_sizes[0] / 4);
    int N = in_sizes[3] / B;
    int nchunk = (P + 255) / 256;
    int nloc = B * nchunk;

    char* w = (char*)d_ws;
    float* conf     = (float*)w;  w += (size_t)B * P * sizeof(float);
    float* locpart  = (float*)w;  w += (size_t)nloc * sizeof(float);
    float* pospart  = (float*)w;  w += (size_t)nloc * sizeof(float);
    int*   nppart   = (int*)w;    w += (size_t)nloc * sizeof(int);
    float* hardpart = (float*)w;  w += (size_t)B * sizeof(float);
    float* locfix   = (float*)w;  w += (size_t)B * sizeof(float);
    float* posfix   = (float*)w;  w += (size_t)B * sizeof(float);
    int*   nposc    = (int*)w;    w += (size_t)B * sizeof(int);
    w = (char*)(((uintptr_t)w + 63) & ~(uintptr_t)63);
    unsigned* acc   = (unsigned*)w;   // 2 words

    dim3 ga(nchunk, B);
    size_t smf = (size_t)256 * C * sizeof(float);
    if (C == 21) {
        k_fused<21><<<ga, 256, smf, stream>>>(plocs, scores, boxes, labels, priors,
                                              P, C, N, nchunk, conf,
                                              locpart, pospart, nppart, acc);
    } else {
        k_fused<0><<<ga, 256, smf, stream>>>(plocs, scores, boxes, labels, priors,
                                             P, C, N, nchunk, conf,
                                             locpart, pospart, nppart, acc);
    }

    k_hard<<<B, 1024, 0, stream>>>(plocs, scores, boxes, labels, priors,
                                   conf, locpart, pospart, nppart,
                                   P, C, N, nchunk, B, nloc,
                                   hardpart, locfix, posfix, nposc,
                                   acc, (float*)d_out);
}